// Round 13
// baseline (159.522 us; speedup 1.0000x reference)
//
#include <hip/hip_runtime.h>

// Local NCC loss on (2,1,160,160,160) f32, 5x5x5 box window, SAME zero pad.
// R13: barrier-free wave-autonomous execution with v10's measured-safe core.
// Block 256 thr = 4 INDEPENDENT waves, each owning a private 32W x 8H x 8D
// sub-tile and private LDS dbuf (4 x 8448 B). ZERO __syncthreads — only
// wave_barrier scheduling fences (R11-validated). amdgpu_waves_per_eu(4,4):
// VGPR budget 128 >= the core's measured 104 liveness (v10/v12) -> no spill
// (R11's failure was 64-thr blocks -> backend targeted 8 waves/EU -> VGPR 64).
// Grid 1000 (XCD-chunked, dz fastest: halo re-reads L2-absorbed, v7/v8).
// Core: aligned f4 staging writes (4 tasks/lane), clean stride-2 b64 reads,
// per-row W-window before vertical sums, compile-time D-phase guards (v8),
// 2Hx2W outputs/thread. Outer a-loop unroll(1) (spill guard).

#define DIM 160
#define SLAB (DIM * DIM)
#define VOL (DIM * DIM * DIM)
#define TD 8
#define ROWS 12                   // staged H rows per wave: 8 + 4 halo
#define RST 44                    // padded row stride (floats)
#define VOFF (ROWS * RST)         // J-volume offset inside a wave buffer
#define WBUF (2 * 2 * ROWS * RST) // floats per wave (2 buf x 2 vol)
#define NBLK 1000
#define NPART (NBLK * 4)

typedef float f4 __attribute__((ext_vector_type(4), aligned(16)));
typedef float f2 __attribute__((ext_vector_type(2), aligned(8)));

// sliding 5-window sums for 2 outputs from 3 f2 (6 consecutive values)
__device__ __forceinline__ f2 hw2(const f2 r0, const f2 r1, const f2 r2) {
    const float c = (r0.y + r1.x) + r1.y;
    return (f2){(r0.x + c) + r2.x, (c + r2.x) + r2.y};
}

__global__ __launch_bounds__(256)
__attribute__((amdgpu_waves_per_eu(4, 4)))
void ncc_main(const float* __restrict__ real,
              const float* __restrict__ fake,
              float* __restrict__ partials) {
    __shared__ __align__(16) float raw[4][WBUF];   // 33792 B, wave-private quarters

    const int tid  = threadIdx.x;
    const int lane = tid & 63;
    const int wid  = tid >> 6;

    // XCD-chunked swizzle: chunk = bid&7 (8 chunks of 125), dz fastest inside.
    const int bid = blockIdx.x;
    const int vid = (bid & 7) * 125 + (bid >> 3);
    const int dz  = vid % 20;
    const int t1  = vid / 20;      // 0..49
    const int bx  = t1 % 5;
    const int by  = (t1 / 5) % 5;
    const int nb  = t1 / 25;
    const int w0 = 32 * bx;
    const int h0 = 32 * by + 8 * wid;   // wave-private H chunk
    const int d0 = TD * dz;

    const float* baseI = real + (size_t)nb * VOL;
    const float* baseJ = fake + (size_t)nb * VOL;

    float* const Lw = &raw[wid][0];     // this wave's LDS

    // compute mapping: sc 0..15 (2-wide W strip), sr 0..3 (rows 2sr, 2sr+1)
    const int sc = lane & 15;
    const int sr = lane >> 4;
    const int co = (2 * sr) * RST + 2 * sc + 2;   // x = 2sc+2 <-> w = w0+2sc-2

    // staging: 240 tasks = 2 vols x 12 rows x 10 quads; 4 per lane (some idle)
    int gof[4], lof[4];
    bool ok[4];
    const float* src[4];
#pragma unroll
    for (int k = 0; k < 4; ++k) {
        const int t   = lane + 64 * k;     // 0..255 (>=240 idle)
        const int tv  = (t < 240) ? (t / 120) : 0;
        const int rem = t - 120 * tv;
        const int row = (rem / 10) % ROWS;
        const int q   = rem - 10 * (rem / 10);
        const int hg  = h0 - 2 + row;
        const int wq  = w0 - 4 + 4 * q;
        ok[k]  = (t < 240) && ((unsigned)hg < DIM) && (wq >= 0) && (wq + 3 < DIM);
        gof[k] = hg * DIM + wq;
        lof[k] = (tv * ROWS + row) * RST + 4 * q;   // ALIGNED f4 slot
        src[k] = tv ? baseJ : baseI;
    }

    // zero this wave's LDS once (never-staged halo/pad slots stay zero)
    for (int i = lane; i < WBUF / 4; i += 64)
        *(f4*)(Lw + 4 * i) = (f4){0.f, 0.f, 0.f, 0.f};
    __builtin_amdgcn_wave_barrier();

    // prologue: stage slab d0-2 into buf0 (d0==0 -> OOB, stays zero)
    if (d0 > 0) {
        const size_t so = (size_t)(d0 - 2) * SLAB;
#pragma unroll
        for (int k = 0; k < 4; ++k)
            if (ok[k]) *(f4*)(Lw + lof[k]) = *(const f4*)(src[k] + so + gof[k]);
    }
    __builtin_amdgcn_wave_barrier();

    const f2 z2 = (f2){0.f, 0.f};
    const f4 zf = (f4){0.f, 0.f, 0.f, 0.f};
    f2 zr0[5][5], zr1[5][5];           // [phase][quantity] per H row, static only
#pragma unroll
    for (int p = 0; p < 5; ++p)
#pragma unroll
        for (int q = 0; q < 5; ++q) { zr0[p][q] = z2; zr1[p][q] = z2; }

    f2 acc = z2;
    const float inv = 1.0f / 125.0f;
    int cur = 0;

#pragma unroll 1
    for (int a = 0; a < 3; ++a) {      // s = 5a+b, slabs 0..11
        const bool am0 = (a > 0);
#pragma unroll
        for (int b = 0; b < 5; ++b) {
            const bool compAct  = (a < 2) || (b < 2);   // s <= 11
            const bool stageAct = (a < 2) || (b == 0);  // s <= 10
            if (!compAct) continue;

            // ---- issue next-slab loads into registers (zeros if D-OOB) ----
            f4 v0 = zf, v1 = zf, v2 = zf, v3 = zf;
            if (stageAct) {
                const int dd1 = d0 - 1 + 5 * a + b;
                if ((unsigned)dd1 < DIM) {
                    const size_t so = (size_t)dd1 * SLAB;
                    if (ok[0]) v0 = *(const f4*)(src[0] + so + gof[0]);
                    if (ok[1]) v1 = *(const f4*)(src[1] + so + gof[1]);
                    if (ok[2]) v2 = *(const f4*)(src[2] + so + gof[2]);
                    if (ok[3]) v3 = *(const f4*)(src[3] + so + gof[3]);
                }
            }

            // ---- compute current slab: per-row W windows, 2 vertical sums ----
            const float* LB = Lw + cur * (2 * VOFF);
            f2 c00 = z2, c01 = z2, c02 = z2, c03 = z2, c04 = z2;   // row 2sr
            f2 c10 = z2, c11 = z2, c12 = z2, c13 = z2, c14 = z2;   // row 2sr+1
#pragma unroll
            for (int t = 0; t < 6; ++t) {
                const float* rp = LB + co + t * RST;
                const f2 a0 = *(const f2*)(rp);
                const f2 a1 = *(const f2*)(rp + 2);
                const f2 a2 = *(const f2*)(rp + 4);
                const f2 b0 = *(const f2*)(rp + VOFF);
                const f2 b1 = *(const f2*)(rp + VOFF + 2);
                const f2 b2 = *(const f2*)(rp + VOFF + 4);
                const f2 w0v = hw2(a0, a1, a2);
                const f2 w1v = hw2(b0, b1, b2);
                const f2 w2v = hw2(a0 * a0, a1 * a1, a2 * a2);
                const f2 w3v = hw2(b0 * b0, b1 * b1, b2 * b2);
                const f2 w4v = hw2(a0 * b0, a1 * b1, a2 * b2);
                if (t < 5) { c00 += w0v; c01 += w1v; c02 += w2v; c03 += w3v; c04 += w4v; }
                if (t > 0) { c10 += w0v; c11 += w1v; c12 += w2v; c13 += w3v; c14 += w4v; }
            }

            // ---- add into active D-phases (guards uniform, indices static) ----
#pragma unroll
            for (int p = 0; p < 5; ++p) {
                const int kk  = (b - p + 5) % 5;   // compile-time
                const int bmk = b - kk;            // compile-time
                const bool doadd = (am0 || p <= b) &&
                                   (a == 0 || (a == 1 ? (bmk <= 2) : (bmk <= -3)));
                if (doadd) {
                    zr0[p][0] += c00; zr0[p][1] += c01; zr0[p][2] += c02;
                    zr0[p][3] += c03; zr0[p][4] += c04;
                    zr1[p][0] += c10; zr1[p][1] += c11; zr1[p][2] += c12;
                    zr1[p][3] += c13; zr1[p][4] += c14;
                }
            }

            // ---- completed output depth od = s-4 -> cc for 2x2 outputs ----
            const bool docomp = (a == 0) ? (b == 4) : ((a == 1) ? true : (b < 2));
            if (docomp) {
                const int pe = (b + 1) % 5;        // compile-time
                {
                    const f2 SI = zr0[pe][0], SJ = zr0[pe][1];
                    const f2 S2I = zr0[pe][2], S2J = zr0[pe][3], SIJ = zr0[pe][4];
                    const f2 t0    = SI * inv;
                    const f2 cross = SIJ - t0 * SJ;
                    const f2 iv    = S2I - t0 * SI;
                    const f2 jv    = S2J - (SJ * inv) * SJ;
                    acc += cross * cross / (iv * jv + 1e-5f);
                    zr0[pe][0] = z2; zr0[pe][1] = z2; zr0[pe][2] = z2;
                    zr0[pe][3] = z2; zr0[pe][4] = z2;
                }
                {
                    const f2 SI = zr1[pe][0], SJ = zr1[pe][1];
                    const f2 S2I = zr1[pe][2], S2J = zr1[pe][3], SIJ = zr1[pe][4];
                    const f2 t0    = SI * inv;
                    const f2 cross = SIJ - t0 * SJ;
                    const f2 iv    = S2I - t0 * SI;
                    const f2 jv    = S2J - (SJ * inv) * SJ;
                    acc += cross * cross / (iv * jv + 1e-5f);
                    zr1[pe][0] = z2; zr1[pe][1] = z2; zr1[pe][2] = z2;
                    zr1[pe][3] = z2; zr1[pe][4] = z2;
                }
            }

            __builtin_amdgcn_wave_barrier();   // buf[cur] reads before writes below

            // ---- write staged regs into other buffer (zeros when D-OOB) ----
            if (stageAct) {
                float* LW = Lw + (cur ^ 1) * (2 * VOFF);
                if (ok[0]) *(f4*)(LW + lof[0]) = v0;
                if (ok[1]) *(f4*)(LW + lof[1]) = v1;
                if (ok[2]) *(f4*)(LW + lof[2]) = v2;
                if (ok[3]) *(f4*)(LW + lof[3]) = v3;
            }
            __builtin_amdgcn_wave_barrier();   // writes before next slab's reads
            cur ^= 1;
        }
    }

    // ---- wave reduction -> one partial per wave ----
    float a2 = acc.x + acc.y;
#pragma unroll
    for (int off = 32; off; off >>= 1)
        a2 += __shfl_down(a2, off, 64);
    if (lane == 0)
        partials[bid * 4 + wid] = a2;
}

__global__ void ncc_reduce(const float* __restrict__ partials, float* __restrict__ out) {
    __shared__ double ws[4];
    double s = 0.0;
    for (int i = threadIdx.x; i < NPART; i += 256) s += (double)partials[i];
#pragma unroll
    for (int off = 32; off; off >>= 1)
        s += __shfl_down(s, off, 64);
    if ((threadIdx.x & 63) == 0) ws[threadIdx.x >> 6] = s;
    __syncthreads();
    if (threadIdx.x == 0) {
        const double t = ws[0] + ws[1] + ws[2] + ws[3];
        out[0] = (float)(t / (2.0 * (double)VOL));
    }
}

extern "C" void kernel_launch(void* const* d_in, const int* in_sizes, int n_in,
                              void* d_out, int out_size, void* d_ws, size_t ws_size,
                              hipStream_t stream) {
    const float* real = (const float*)d_in[0];
    const float* fake = (const float*)d_in[1];
    float* out      = (float*)d_out;
    float* partials = (float*)d_ws;   // NPART floats

    ncc_main<<<dim3(NBLK), dim3(256), 0, stream>>>(real, fake, partials);
    ncc_reduce<<<1, 256, 0, stream>>>(partials, out);
}

// Round 14
// 55.699 us; speedup vs baseline: 2.8640x; 2.8640x over previous
//
#include <hip/hip_runtime.h>

// Local NCC loss on (2,1,160,160,160) f32, 5x5x5 box window, SAME zero pad.
// R14 = R13 (barrier-free wave-autonomous, v10 core) with the PROVEN register
// pin __launch_bounds__(256,2) (v5/v8/v10: VGPR~100, no spill) instead of
// waves_per_eu(4,4) (R13: VGPR=64, 405MB scratch spill).
// Block 256 thr = 4 INDEPENDENT waves, each owning a private 32W x 8H x 8D
// sub-tile and private LDS dbuf (4 x 8448 B). ZERO __syncthreads — only
// wave_barrier scheduling fences. Grid 1000 (XCD-chunked, dz fastest).
// Core: aligned f4 staging writes (4 tasks/lane), clean stride-2 b64 reads,
// per-row W-window before vertical sums, compile-time D-phase guards,
// 2Hx2W outputs/thread. Outer a-loop unroll(1) (spill guard).

#define DIM 160
#define SLAB (DIM * DIM)
#define VOL (DIM * DIM * DIM)
#define TD 8
#define ROWS 12                   // staged H rows per wave: 8 + 4 halo
#define RST 44                    // padded row stride (floats)
#define VOFF (ROWS * RST)         // J-volume offset inside a wave buffer
#define WBUF (2 * 2 * ROWS * RST) // floats per wave (2 buf x 2 vol)
#define NBLK 1000
#define NPART (NBLK * 4)

typedef float f4 __attribute__((ext_vector_type(4), aligned(16)));
typedef float f2 __attribute__((ext_vector_type(2), aligned(8)));

// sliding 5-window sums for 2 outputs from 3 f2 (6 consecutive values)
__device__ __forceinline__ f2 hw2(const f2 r0, const f2 r1, const f2 r2) {
    const float c = (r0.y + r1.x) + r1.y;
    return (f2){(r0.x + c) + r2.x, (c + r2.x) + r2.y};
}

__global__ __launch_bounds__(256, 2)
void ncc_main(const float* __restrict__ real,
              const float* __restrict__ fake,
              float* __restrict__ partials) {
    __shared__ __align__(16) float raw[4][WBUF];   // 33792 B, wave-private quarters

    const int tid  = threadIdx.x;
    const int lane = tid & 63;
    const int wid  = tid >> 6;

    // XCD-chunked swizzle: chunk = bid&7 (8 chunks of 125), dz fastest inside.
    const int bid = blockIdx.x;
    const int vid = (bid & 7) * 125 + (bid >> 3);
    const int dz  = vid % 20;
    const int t1  = vid / 20;      // 0..49
    const int bx  = t1 % 5;
    const int by  = (t1 / 5) % 5;
    const int nb  = t1 / 25;
    const int w0 = 32 * bx;
    const int h0 = 32 * by + 8 * wid;   // wave-private H chunk
    const int d0 = TD * dz;

    const float* baseI = real + (size_t)nb * VOL;
    const float* baseJ = fake + (size_t)nb * VOL;

    float* const Lw = &raw[wid][0];     // this wave's LDS

    // compute mapping: sc 0..15 (2-wide W strip), sr 0..3 (rows 2sr, 2sr+1)
    const int sc = lane & 15;
    const int sr = lane >> 4;
    const int co = (2 * sr) * RST + 2 * sc + 2;   // x = 2sc+2 <-> w = w0+2sc-2

    // staging: 240 tasks = 2 vols x 12 rows x 10 quads; 4 per lane (some idle)
    int gof[4], lof[4];
    bool ok[4];
    const float* src[4];
#pragma unroll
    for (int k = 0; k < 4; ++k) {
        const int t   = lane + 64 * k;     // 0..255 (>=240 idle)
        const int tv  = (t < 240) ? (t / 120) : 0;
        const int rem = t - 120 * tv;
        const int row = (rem / 10) % ROWS;
        const int q   = rem - 10 * (rem / 10);
        const int hg  = h0 - 2 + row;
        const int wq  = w0 - 4 + 4 * q;
        ok[k]  = (t < 240) && ((unsigned)hg < DIM) && (wq >= 0) && (wq + 3 < DIM);
        gof[k] = hg * DIM + wq;
        lof[k] = (tv * ROWS + row) * RST + 4 * q;   // ALIGNED f4 slot
        src[k] = tv ? baseJ : baseI;
    }

    // zero this wave's LDS once (never-staged halo/pad slots stay zero)
    for (int i = lane; i < WBUF / 4; i += 64)
        *(f4*)(Lw + 4 * i) = (f4){0.f, 0.f, 0.f, 0.f};
    __builtin_amdgcn_wave_barrier();

    // prologue: stage slab d0-2 into buf0 (d0==0 -> OOB, stays zero)
    if (d0 > 0) {
        const size_t so = (size_t)(d0 - 2) * SLAB;
#pragma unroll
        for (int k = 0; k < 4; ++k)
            if (ok[k]) *(f4*)(Lw + lof[k]) = *(const f4*)(src[k] + so + gof[k]);
    }
    __builtin_amdgcn_wave_barrier();

    const f2 z2 = (f2){0.f, 0.f};
    const f4 zf = (f4){0.f, 0.f, 0.f, 0.f};
    f2 zr0[5][5], zr1[5][5];           // [phase][quantity] per H row, static only
#pragma unroll
    for (int p = 0; p < 5; ++p)
#pragma unroll
        for (int q = 0; q < 5; ++q) { zr0[p][q] = z2; zr1[p][q] = z2; }

    f2 acc = z2;
    const float inv = 1.0f / 125.0f;
    int cur = 0;

#pragma unroll 1
    for (int a = 0; a < 3; ++a) {      // s = 5a+b, slabs 0..11
        const bool am0 = (a > 0);
#pragma unroll
        for (int b = 0; b < 5; ++b) {
            const bool compAct  = (a < 2) || (b < 2);   // s <= 11
            const bool stageAct = (a < 2) || (b == 0);  // s <= 10
            if (!compAct) continue;

            // ---- issue next-slab loads into registers (zeros if D-OOB) ----
            f4 v0 = zf, v1 = zf, v2 = zf, v3 = zf;
            if (stageAct) {
                const int dd1 = d0 - 1 + 5 * a + b;
                if ((unsigned)dd1 < DIM) {
                    const size_t so = (size_t)dd1 * SLAB;
                    if (ok[0]) v0 = *(const f4*)(src[0] + so + gof[0]);
                    if (ok[1]) v1 = *(const f4*)(src[1] + so + gof[1]);
                    if (ok[2]) v2 = *(const f4*)(src[2] + so + gof[2]);
                    if (ok[3]) v3 = *(const f4*)(src[3] + so + gof[3]);
                }
            }

            // ---- compute current slab: per-row W windows, 2 vertical sums ----
            const float* LB = Lw + cur * (2 * VOFF);
            f2 c00 = z2, c01 = z2, c02 = z2, c03 = z2, c04 = z2;   // row 2sr
            f2 c10 = z2, c11 = z2, c12 = z2, c13 = z2, c14 = z2;   // row 2sr+1
#pragma unroll
            for (int t = 0; t < 6; ++t) {
                const float* rp = LB + co + t * RST;
                const f2 a0 = *(const f2*)(rp);
                const f2 a1 = *(const f2*)(rp + 2);
                const f2 a2 = *(const f2*)(rp + 4);
                const f2 b0 = *(const f2*)(rp + VOFF);
                const f2 b1 = *(const f2*)(rp + VOFF + 2);
                const f2 b2 = *(const f2*)(rp + VOFF + 4);
                const f2 w0v = hw2(a0, a1, a2);
                const f2 w1v = hw2(b0, b1, b2);
                const f2 w2v = hw2(a0 * a0, a1 * a1, a2 * a2);
                const f2 w3v = hw2(b0 * b0, b1 * b1, b2 * b2);
                const f2 w4v = hw2(a0 * b0, a1 * b1, a2 * b2);
                if (t < 5) { c00 += w0v; c01 += w1v; c02 += w2v; c03 += w3v; c04 += w4v; }
                if (t > 0) { c10 += w0v; c11 += w1v; c12 += w2v; c13 += w3v; c14 += w4v; }
            }

            // ---- add into active D-phases (guards uniform, indices static) ----
#pragma unroll
            for (int p = 0; p < 5; ++p) {
                const int kk  = (b - p + 5) % 5;   // compile-time
                const int bmk = b - kk;            // compile-time
                const bool doadd = (am0 || p <= b) &&
                                   (a == 0 || (a == 1 ? (bmk <= 2) : (bmk <= -3)));
                if (doadd) {
                    zr0[p][0] += c00; zr0[p][1] += c01; zr0[p][2] += c02;
                    zr0[p][3] += c03; zr0[p][4] += c04;
                    zr1[p][0] += c10; zr1[p][1] += c11; zr1[p][2] += c12;
                    zr1[p][3] += c13; zr1[p][4] += c14;
                }
            }

            // ---- completed output depth od = s-4 -> cc for 2x2 outputs ----
            const bool docomp = (a == 0) ? (b == 4) : ((a == 1) ? true : (b < 2));
            if (docomp) {
                const int pe = (b + 1) % 5;        // compile-time
                {
                    const f2 SI = zr0[pe][0], SJ = zr0[pe][1];
                    const f2 S2I = zr0[pe][2], S2J = zr0[pe][3], SIJ = zr0[pe][4];
                    const f2 t0    = SI * inv;
                    const f2 cross = SIJ - t0 * SJ;
                    const f2 iv    = S2I - t0 * SI;
                    const f2 jv    = S2J - (SJ * inv) * SJ;
                    acc += cross * cross / (iv * jv + 1e-5f);
                    zr0[pe][0] = z2; zr0[pe][1] = z2; zr0[pe][2] = z2;
                    zr0[pe][3] = z2; zr0[pe][4] = z2;
                }
                {
                    const f2 SI = zr1[pe][0], SJ = zr1[pe][1];
                    const f2 S2I = zr1[pe][2], S2J = zr1[pe][3], SIJ = zr1[pe][4];
                    const f2 t0    = SI * inv;
                    const f2 cross = SIJ - t0 * SJ;
                    const f2 iv    = S2I - t0 * SI;
                    const f2 jv    = S2J - (SJ * inv) * SJ;
                    acc += cross * cross / (iv * jv + 1e-5f);
                    zr1[pe][0] = z2; zr1[pe][1] = z2; zr1[pe][2] = z2;
                    zr1[pe][3] = z2; zr1[pe][4] = z2;
                }
            }

            __builtin_amdgcn_wave_barrier();   // buf[cur] reads before writes below

            // ---- write staged regs into other buffer (zeros when D-OOB) ----
            if (stageAct) {
                float* LW = Lw + (cur ^ 1) * (2 * VOFF);
                if (ok[0]) *(f4*)(LW + lof[0]) = v0;
                if (ok[1]) *(f4*)(LW + lof[1]) = v1;
                if (ok[2]) *(f4*)(LW + lof[2]) = v2;
                if (ok[3]) *(f4*)(LW + lof[3]) = v3;
            }
            __builtin_amdgcn_wave_barrier();   // writes before next slab's reads
            cur ^= 1;
        }
    }

    // ---- wave reduction -> one partial per wave ----
    float a2 = acc.x + acc.y;
#pragma unroll
    for (int off = 32; off; off >>= 1)
        a2 += __shfl_down(a2, off, 64);
    if (lane == 0)
        partials[bid * 4 + wid] = a2;
}

__global__ void ncc_reduce(const float* __restrict__ partials, float* __restrict__ out) {
    __shared__ double ws[4];
    double s = 0.0;
    for (int i = threadIdx.x; i < NPART; i += 256) s += (double)partials[i];
#pragma unroll
    for (int off = 32; off; off >>= 1)
        s += __shfl_down(s, off, 64);
    if ((threadIdx.x & 63) == 0) ws[threadIdx.x >> 6] = s;
    __syncthreads();
    if (threadIdx.x == 0) {
        const double t = ws[0] + ws[1] + ws[2] + ws[3];
        out[0] = (float)(t / (2.0 * (double)VOL));
    }
}

extern "C" void kernel_launch(void* const* d_in, const int* in_sizes, int n_in,
                              void* d_out, int out_size, void* d_ws, size_t ws_size,
                              hipStream_t stream) {
    const float* real = (const float*)d_in[0];
    const float* fake = (const float*)d_in[1];
    float* out      = (float*)d_out;
    float* partials = (float*)d_ws;   // NPART floats

    ncc_main<<<dim3(NBLK), dim3(256), 0, stream>>>(real, fake, partials);
    ncc_reduce<<<1, 256, 0, stream>>>(partials, out);
}